// Round 1
// baseline (13479.855 us; speedup 1.0000x reference)
//
#include <hip/hip_runtime.h>
#include <math.h>

#define BB 16
#define NN 512   // seq1 rows = columns of the transposed LSA problem
#define MM 448   // seq2 rows = rows of the transposed LSA problem
#define DD 1536

// ---------------------------------------------------------------------------
// Cost kernel: Ct[b][j][i] = ||seq1[b,i,:] - seq2[b,j,:]||  (float32)
// 64x64 output tile per 256-thread block, 4x4 register blocking, k-major LDS
// so fragment reads are ds_read_b128. f32 inner partials (32 k) folded into
// f64 totals -> accumulation error ~1e-4 in d^2, ~1e-6 in d.
// ---------------------------------------------------------------------------
constexpr int TK = 32;

__global__ __launch_bounds__(256) void cost_kernel(const float* __restrict__ s1,
                                                   const float* __restrict__ s2,
                                                   float* __restrict__ Ct) {
  __shared__ float As[TK][68];  // [k][i], pad 68 to keep 16B-aligned rows
  __shared__ float Bs[TK][68];  // [k][j]
  const int b = blockIdx.z;
  const int ibase = blockIdx.x * 64;
  const int jbase = blockIdx.y * 64;
  const int tid = threadIdx.x;
  const float* s1b = s1 + ((size_t)b * NN + ibase) * DD;
  const float* s2b = s2 + ((size_t)b * MM + jbase) * DD;
  const int ix = (tid & 15) * 4;
  const int jy = (tid >> 4) * 4;
  double acc[16];
#pragma unroll
  for (int t = 0; t < 16; ++t) acc[t] = 0.0;

  for (int k0 = 0; k0 < DD; k0 += TK) {
#pragma unroll
    for (int rep = 0; rep < 2; ++rep) {
      int idx = tid + rep * 256;        // 0..511
      int r = idx >> 3;                 // 0..63 (row within tile)
      int c4 = (idx & 7) * 4;           // 0..28 (k offset)
      float4 a = *(const float4*)(s1b + (size_t)r * DD + k0 + c4);
      As[c4 + 0][r] = a.x; As[c4 + 1][r] = a.y; As[c4 + 2][r] = a.z; As[c4 + 3][r] = a.w;
      float4 bb = *(const float4*)(s2b + (size_t)r * DD + k0 + c4);
      Bs[c4 + 0][r] = bb.x; Bs[c4 + 1][r] = bb.y; Bs[c4 + 2][r] = bb.z; Bs[c4 + 3][r] = bb.w;
    }
    __syncthreads();
    float pacc[16];
#pragma unroll
    for (int t = 0; t < 16; ++t) pacc[t] = 0.f;
#pragma unroll 8
    for (int kk = 0; kk < TK; ++kk) {
      float4 av = *(const float4*)&As[kk][ix];
      float4 bv = *(const float4*)&Bs[kk][jy];
      float a[4] = {av.x, av.y, av.z, av.w};
      float bq[4] = {bv.x, bv.y, bv.z, bv.w};
#pragma unroll
      for (int t = 0; t < 4; ++t)
#pragma unroll
        for (int q = 0; q < 4; ++q) {
          float d = a[t] - bq[q];
          pacc[t * 4 + q] = fmaf(d, d, pacc[t * 4 + q]);
        }
    }
#pragma unroll
    for (int t = 0; t < 16; ++t) acc[t] += (double)pacc[t];
    __syncthreads();
  }
#pragma unroll
  for (int t = 0; t < 4; ++t)
#pragma unroll
    for (int q = 0; q < 4; ++q) {
      int i = ibase + ix + t;
      int jj = jbase + jy + q;
      float d2 = (float)acc[t * 4 + q];
      Ct[((size_t)b * MM + jj) * NN + i] = sqrtf(fmaxf(d2, 0.f));
    }
}

// ---------------------------------------------------------------------------
// JV / Hungarian (e-maxx with potentials), one 512-thread block per batch.
// Thread tid owns column j = tid+1. minv/way-candidate/used/v live in
// registers; u, p, way in LDS. Mirrors the reference float64 arithmetic and
// first-index argmin tie-break exactly.
// ---------------------------------------------------------------------------
__global__ __launch_bounds__(512) void jv_kernel(const float* __restrict__ Ct,
                                                 int* __restrict__ perm) {
  const int b = blockIdx.x;
  const float* C = Ct + (size_t)b * MM * NN;
  __shared__ double u[MM + 1];
  __shared__ int p[NN + 1];
  __shared__ int way[NN + 1];
  __shared__ double wred[8];
  __shared__ int wredi[8];
  __shared__ double delta_s;
  __shared__ int j1_s;
  __shared__ int scan[NN];
  const int tid = threadIdx.x;   // 0..511
  const int j = tid + 1;         // owned column, 1-based
  const int lane = tid & 63;
  const int wave = tid >> 6;

  if (tid <= MM) u[tid] = 0.0;
  p[j] = 0;
  way[j] = 0;
  if (tid == 0) { p[0] = 0; way[0] = 0; }
  double v_j = 0.0;
  __syncthreads();

  for (int i = 1; i <= MM; ++i) {
    if (tid == 0) p[0] = i;
    double minv_j = 1e18;
    bool used_j = false;
    int j0 = 0;
    __syncthreads();
    while (true) {
      if (j == j0) used_j = true;        // mark current column used
      const int i0 = p[j0];              // uniform
      const double uu = u[i0];
      double cand = 1e18;
      if (!used_j) {
        double cur = ((double)C[(size_t)(i0 - 1) * NN + (j - 1)] - uu) - v_j;
        if (cur < minv_j) { minv_j = cur; way[j] = j0; }
        cand = minv_j;
      }
      // argmin (value, first index) over 512 threads
      double rv = cand; int ri = j;
#pragma unroll
      for (int off = 32; off > 0; off >>= 1) {
        double ov = __shfl_down(rv, off, 64);
        int oi = __shfl_down(ri, off, 64);
        if (ov < rv || (ov == rv && oi < ri)) { rv = ov; ri = oi; }
      }
      if (lane == 0) { wred[wave] = rv; wredi[wave] = ri; }
      __syncthreads();
      if (tid == 0) {
        double bv = wred[0]; int bi = wredi[0];
#pragma unroll
        for (int w = 1; w < 8; ++w)
          if (wred[w] < bv || (wred[w] == bv && wredi[w] < bi)) { bv = wred[w]; bi = wredi[w]; }
        delta_s = bv; j1_s = bi;
      }
      __syncthreads();
      const double delta = delta_s;
      const int j1 = j1_s;
      if (used_j) { u[p[j]] += delta; v_j -= delta; }  // distinct rows -> no conflict
      else { minv_j -= delta; }
      if (tid == 0) u[i] += delta;                      // dummy column 0 (p[0] == i)
      __syncthreads();
      j0 = j1;
      if (p[j0] == 0) break;
    }
    if (tid == 0) {                                     // augment along way[]
      int jj = j0;
      while (jj != 0) { const int jp = way[jj]; p[jj] = p[jp]; jj = jp; }
    }
    __syncthreads();
  }

  // perm = matched original rows (= assigned columns) ascending, then rest
  const int matched = (p[j] != 0) ? 1 : 0;
  scan[tid] = matched;
  __syncthreads();
  for (int off = 1; off < NN; off <<= 1) {
    int val = scan[tid];
    int add = (tid >= off) ? scan[tid - off] : 0;
    __syncthreads();
    scan[tid] = val + add;
    __syncthreads();
  }
  const int incl = scan[tid];
  const int total = scan[NN - 1];   // = 448
  const int pos = matched ? (incl - 1) : (total + tid - incl);
  perm[b * NN + pos] = tid;
}

// ---------------------------------------------------------------------------
// Gather: out[b,i,:] = seq1[b, perm[b][i], :]
// ---------------------------------------------------------------------------
__global__ __launch_bounds__(256) void gather_kernel(const float* __restrict__ s1,
                                                     const int* __restrict__ perm,
                                                     float* __restrict__ out) {
  const int bi = blockIdx.x;          // b*512 + i
  const int b = bi >> 9;
  const int src = perm[bi];
  const float4* sp = (const float4*)(s1 + ((size_t)b * NN + src) * DD);
  float4* dp = (float4*)(out + (size_t)bi * DD);
  for (int t = threadIdx.x; t < DD / 4; t += 256) dp[t] = sp[t];
}

extern "C" void kernel_launch(void* const* d_in, const int* in_sizes, int n_in,
                              void* d_out, int out_size, void* d_ws, size_t ws_size,
                              hipStream_t stream) {
  const float* s1 = (const float*)d_in[0];
  const float* s2 = (const float*)d_in[1];
  float* out = (float*)d_out;
  // Stage the cost matrix in d_out (16*448*512 floats = 14.7 MB << 50 MB);
  // the gather overwrites it afterwards. perm lives in the workspace.
  float* Ct = (float*)d_out;
  int* perm = (int*)d_ws;

  dim3 cg(NN / 64, MM / 64, BB);
  cost_kernel<<<cg, 256, 0, stream>>>(s1, s2, Ct);
  jv_kernel<<<BB, NN, 0, stream>>>(Ct, perm);
  gather_kernel<<<BB * NN, 256, 0, stream>>>(s1, perm, out);
}

// Round 2
// 7981.733 us; speedup vs baseline: 1.6888x; 1.6888x over previous
//
#include <hip/hip_runtime.h>
#include <math.h>

#define BB 16
#define NN 512   // seq1 rows = columns of the transposed LSA problem
#define MM 448   // seq2 rows = rows of the transposed LSA problem
#define DD 1536

// ---------------------------------------------------------------------------
// Cost kernel: Ct[b][j][i] = ||seq1[b,i,:] - seq2[b,j,:]||  (float32)
// Unchanged from the passing round-1 version.
// ---------------------------------------------------------------------------
constexpr int TK = 32;

__global__ __launch_bounds__(256) void cost_kernel(const float* __restrict__ s1,
                                                   const float* __restrict__ s2,
                                                   float* __restrict__ Ct) {
  __shared__ float As[TK][68];
  __shared__ float Bs[TK][68];
  const int b = blockIdx.z;
  const int ibase = blockIdx.x * 64;
  const int jbase = blockIdx.y * 64;
  const int tid = threadIdx.x;
  const float* s1b = s1 + ((size_t)b * NN + ibase) * DD;
  const float* s2b = s2 + ((size_t)b * MM + jbase) * DD;
  const int ix = (tid & 15) * 4;
  const int jy = (tid >> 4) * 4;
  double acc[16];
#pragma unroll
  for (int t = 0; t < 16; ++t) acc[t] = 0.0;

  for (int k0 = 0; k0 < DD; k0 += TK) {
#pragma unroll
    for (int rep = 0; rep < 2; ++rep) {
      int idx = tid + rep * 256;
      int r = idx >> 3;
      int c4 = (idx & 7) * 4;
      float4 a = *(const float4*)(s1b + (size_t)r * DD + k0 + c4);
      As[c4 + 0][r] = a.x; As[c4 + 1][r] = a.y; As[c4 + 2][r] = a.z; As[c4 + 3][r] = a.w;
      float4 bb = *(const float4*)(s2b + (size_t)r * DD + k0 + c4);
      Bs[c4 + 0][r] = bb.x; Bs[c4 + 1][r] = bb.y; Bs[c4 + 2][r] = bb.z; Bs[c4 + 3][r] = bb.w;
    }
    __syncthreads();
    float pacc[16];
#pragma unroll
    for (int t = 0; t < 16; ++t) pacc[t] = 0.f;
#pragma unroll 8
    for (int kk = 0; kk < TK; ++kk) {
      float4 av = *(const float4*)&As[kk][ix];
      float4 bv = *(const float4*)&Bs[kk][jy];
      float a[4] = {av.x, av.y, av.z, av.w};
      float bq[4] = {bv.x, bv.y, bv.z, bv.w};
#pragma unroll
      for (int t = 0; t < 4; ++t)
#pragma unroll
        for (int q = 0; q < 4; ++q) {
          float d = a[t] - bq[q];
          pacc[t * 4 + q] = fmaf(d, d, pacc[t * 4 + q]);
        }
    }
#pragma unroll
    for (int t = 0; t < 16; ++t) acc[t] += (double)pacc[t];
    __syncthreads();
  }
#pragma unroll
  for (int t = 0; t < 4; ++t)
#pragma unroll
    for (int q = 0; q < 4; ++q) {
      int i = ibase + ix + t;
      int jj = jbase + jy + q;
      float d2 = (float)acc[t * 4 + q];
      Ct[((size_t)b * MM + jj) * NN + i] = sqrtf(fmaxf(d2, 0.f));
    }
}

// ---------------------------------------------------------------------------
// Wave-wide f64 min via DPP (row_shr 1/2/4/8 + row_bcast 15/31, old = +1e18),
// result broadcast to all lanes via readlane(63). Min only copies bit
// patterns, so the result is bit-identical to one lane's input.
// ---------------------------------------------------------------------------
__device__ __forceinline__ double wave_min_bcast_f64(double x) {
  union DU { double d; unsigned int u[2]; };
  DU v; v.d = x;
  DU inf; inf.d = 1e18;
#define DPP_STEP(CTRL) { DU o; \
  o.u[0] = (unsigned)__builtin_amdgcn_update_dpp((int)inf.u[0], (int)v.u[0], CTRL, 0xF, 0xF, false); \
  o.u[1] = (unsigned)__builtin_amdgcn_update_dpp((int)inf.u[1], (int)v.u[1], CTRL, 0xF, 0xF, false); \
  if (o.d < v.d) v.d = o.d; }
  DPP_STEP(0x111)  // row_shr:1
  DPP_STEP(0x112)  // row_shr:2
  DPP_STEP(0x114)  // row_shr:4
  DPP_STEP(0x118)  // row_shr:8
  DPP_STEP(0x142)  // row_bcast:15
  DPP_STEP(0x143)  // row_bcast:31
#undef DPP_STEP
  DU r;
  r.u[0] = (unsigned)__builtin_amdgcn_readlane((int)v.u[0], 63);
  r.u[1] = (unsigned)__builtin_amdgcn_readlane((int)v.u[1], 63);
  return r.d;
}

// ---------------------------------------------------------------------------
// JV / Hungarian, ONE WAVE (64 lanes) per batch. Lane owns 8 consecutive
// columns (j = 8*lane+1 .. 8*lane+8), so each cost-row read is 2 coalesced
// dwordx4 loads. No __syncthreads anywhere; explicit lgkmcnt waits at row
// boundaries. u/v potential updates are deferred to row end (within one
// row's Dijkstra, u[i0] of a newly popped row is never modified by that
// row's earlier deltas), tracked via running cum and mark-time snapshots.
// f64 math mirrors the reference exactly, incl. first-index argmin ties.
// ---------------------------------------------------------------------------
__global__ __launch_bounds__(64) void jv_kernel(const float* __restrict__ Ct,
                                                int* __restrict__ perm) {
  const int b = blockIdx.x;
  const float* C = Ct + (size_t)b * MM * NN;
  __shared__ double u_lds[MM + 1];
  __shared__ int p_lds[NN + 1];
  __shared__ int way_lds[NN + 1];
  __shared__ int cnt_lds[64];
  const int lane = threadIdx.x;
  const int jbase = 8 * lane + 1;   // owned columns, 1-based

  for (int t = lane; t <= MM; t += 64) u_lds[t] = 0.0;
  for (int t = lane; t <= NN; t += 64) { p_lds[t] = 0; way_lds[t] = 0; }
  double vcol[8];
#pragma unroll
  for (int q = 0; q < 8; ++q) vcol[q] = 0.0;
  asm volatile("s_waitcnt lgkmcnt(0)" ::: "memory");

  for (int i = 1; i <= MM; ++i) {
    if (lane == 0) p_lds[0] = i;
    double minv[8], rec[8];
    int preg[8];
#pragma unroll
    for (int q = 0; q < 8; ++q) { minv[q] = 1e18; rec[q] = 0.0; preg[q] = 0; }
    int usedm = 0;
    double cum = 0.0;
    int j0 = 0, i0 = i;

    while (true) {
      // mark column j0 used; snapshot cum (delta of this step IS applied to it)
#pragma unroll
      for (int q = 0; q < 8; ++q)
        if (j0 == jbase + q) { usedm |= (1 << q); preg[q] = i0; rec[q] = cum; }

      const float4* r4 = (const float4*)(C + (size_t)(i0 - 1) * NN);
      float4 ca = r4[2 * lane];
      float4 cb = r4[2 * lane + 1];
      double uu = u_lds[i0];
      float c[8] = {ca.x, ca.y, ca.z, ca.w, cb.x, cb.y, cb.z, cb.w};
#pragma unroll
      for (int q = 0; q < 8; ++q) {
        if (!((usedm >> q) & 1)) {
          double cur = ((double)c[q] - uu) - vcol[q];
          if (cur < minv[q]) { minv[q] = cur; way_lds[jbase + q] = j0; }
        }
      }
      // local argmin over unused (ascending q => first-index tie-break)
      double cand = 1e18; int argj = 0;
#pragma unroll
      for (int q = 0; q < 8; ++q) {
        double mq = ((usedm >> q) & 1) ? 1e18 : minv[q];
        if (mq < cand) { cand = mq; argj = jbase + q; }
      }
      double delta = wave_min_bcast_f64(cand);
      unsigned long long bm = __ballot(cand == delta);
      int sl = (int)__ffsll((unsigned long long)bm) - 1;
      int j1 = __builtin_amdgcn_readlane(argj, sl);
      cum += delta;
#pragma unroll
      for (int q = 0; q < 8; ++q)
        if (!((usedm >> q) & 1)) minv[q] -= delta;
      int pn = p_lds[j1];
      j0 = j1;
      if (pn == 0) break;
      i0 = pn;
    }

    // flush deferred u/v updates (distinct addresses across all used cols + i)
    if (lane == 0) u_lds[i] += cum;
#pragma unroll
    for (int q = 0; q < 8; ++q)
      if ((usedm >> q) & 1) {
        double d = cum - rec[q];
        vcol[q] -= d;
        u_lds[preg[q]] += d;
      }
    asm volatile("s_waitcnt lgkmcnt(0)" ::: "memory");
    if (lane == 0) {   // augment along way[]
      int jj = j0;
      while (jj != 0) { int jp = way_lds[jj]; p_lds[jj] = p_lds[jp]; jj = jp; }
    }
    asm volatile("s_waitcnt lgkmcnt(0)" ::: "memory");
  }

  // perm = matched cols (assigned seq1 rows) ascending, then unmatched ascending
  int mask = 0, cnt = 0;
#pragma unroll
  for (int q = 0; q < 8; ++q)
    if (p_lds[jbase + q] != 0) { mask |= 1 << q; cnt++; }
  cnt_lds[lane] = cnt;
  asm volatile("s_waitcnt lgkmcnt(0)" ::: "memory");
  int pre = 0;
  for (int l = 0; l < 64; ++l) { int cl = cnt_lds[l]; if (l < lane) pre += cl; }
  int mpos = pre;
  int upos = MM + (8 * lane - pre);
#pragma unroll
  for (int q = 0; q < 8; ++q) {
    int col = 8 * lane + q;
    if ((mask >> q) & 1) perm[b * NN + mpos++] = col;
    else                 perm[b * NN + upos++] = col;
  }
}

// ---------------------------------------------------------------------------
// Gather: out[b,i,:] = seq1[b, perm[b][i], :]
// ---------------------------------------------------------------------------
__global__ __launch_bounds__(256) void gather_kernel(const float* __restrict__ s1,
                                                     const int* __restrict__ perm,
                                                     float* __restrict__ out) {
  const int bi = blockIdx.x;
  const int b = bi >> 9;
  const int src = perm[bi];
  const float4* sp = (const float4*)(s1 + ((size_t)b * NN + src) * DD);
  float4* dp = (float4*)(out + (size_t)bi * DD);
  for (int t = threadIdx.x; t < DD / 4; t += 256) dp[t] = sp[t];
}

extern "C" void kernel_launch(void* const* d_in, const int* in_sizes, int n_in,
                              void* d_out, int out_size, void* d_ws, size_t ws_size,
                              hipStream_t stream) {
  const float* s1 = (const float*)d_in[0];
  const float* s2 = (const float*)d_in[1];
  float* out = (float*)d_out;
  float* Ct = (float*)d_out;       // staged cost matrix, overwritten by gather
  int* perm = (int*)d_ws;

  dim3 cg(NN / 64, MM / 64, BB);
  cost_kernel<<<cg, 256, 0, stream>>>(s1, s2, Ct);
  jv_kernel<<<BB, 64, 0, stream>>>(Ct, perm);
  gather_kernel<<<BB * NN, 256, 0, stream>>>(s1, perm, out);
}